// Round 9
// baseline (651.600 us; speedup 1.0000x reference)
//
#include <hip/hip_runtime.h>
#include <hip/hip_bf16.h>

// PINN fused forward+jvp^2 via split-fp16 MFMA.
// R9: explicit 2-stage register double-buffer of the per-kt operands, now that
// the 512-thread/(512,4) shape gives 128 regs/wave (R5's attempt at 1024thr/64reg
// spilled). B-planes (LDS) dbuf'd in all layers; A (global, L2-hot) dbuf'd where
// NMT<=2, issued-early for L3 (NMT=4, dbuf would exceed 128 regs).
// Structure otherwise = R8: 4 LDS planes (vhi,vlo,dhi,ddh), 2 blocks/CU,
// 5 MFMA per (kt,mt): v = 3-product split-fp16, d/dd = plain fp16.

#define NSAMP 65536
#define Q     100
#define DTC   0.8f
#define BS    16
#define THREADS 512
#define STR   520          // plane stride (halves); 520*2B: 16-lane b128 pattern = 2-way (free)

typedef _Float16 h8 __attribute__((ext_vector_type(8)));
typedef _Float16 h4 __attribute__((ext_vector_type(4)));
typedef float    f4 __attribute__((ext_vector_type(4)));

// ---- padded weight-plane geometry (halves), Mp = max(ceil16(FOUT), Kp_next) ----
#define S1 (64*32)
#define S2 (224*64)
#define S3 (512*224)
#define S4 (224*512)
#define S5 (112*224)
#define SW (S1+S2+S3+S4+S5)      // 270848 halves per plane
#define C1 0
#define C2 (C1+S1)
#define C3 (C2+S2)
#define C4 (C3+S3)
#define C5 (C4+S4)
#define BP1 0
#define BP2 64
#define BP3 288
#define BP4 800
#define BP5 1024
#define BPTOT 1136
#define WS_BIAS_BYTE_OFF (SW*2*2)

__device__ __forceinline__ float fast_tanh(float z) {
    float az = fabsf(z);
    float e  = __expf(-2.0f * az);
    float r  = __builtin_amdgcn_rcpf(1.0f + e);
    float t  = (1.0f - e) * r;
    return copysignf(t, z);
}

struct Split { _Float16 hi, lo; };
__device__ __forceinline__ Split split16(float v) {
    Split s;
    s.hi = (_Float16)v;
    s.lo = (_Float16)(v - (float)s.hi);
    return s;
}

// ---------------- pre-pass: split/pad weights + biases into d_ws ----------------
__global__ __launch_bounds__(256) void prepass(
    const float* __restrict__ W1, const float* __restrict__ b1,
    const float* __restrict__ W2, const float* __restrict__ b2,
    const float* __restrict__ W3, const float* __restrict__ b3,
    const float* __restrict__ W4, const float* __restrict__ b4,
    const float* __restrict__ W5, const float* __restrict__ b5,
    _Float16* __restrict__ whi, float* __restrict__ biasP)
{
    int idx = blockIdx.x * 256 + threadIdx.x;
    _Float16* wlo = whi + SW;
    if (idx < SW) {
        int base, Kp, K, FOUT; const float* W;
        if      (idx < C2) { base=C1; Kp=32;  K=20;  FOUT=50;  W=W1; }
        else if (idx < C3) { base=C2; Kp=64;  K=50;  FOUT=200; W=W2; }
        else if (idx < C4) { base=C3; Kp=224; K=200; FOUT=500; W=W3; }
        else if (idx < C5) { base=C4; Kp=512; K=500; FOUT=200; W=W4; }
        else               { base=C5; Kp=224; K=200; FOUT=100; W=W5; }
        int r = idx - base;
        int o = r / Kp;
        int k = r - o * Kp;
        float v = (o < FOUT && k < K) ? W[o * K + k] : 0.f;
        Split sp = split16(v);
        whi[idx] = sp.hi; wlo[idx] = sp.lo;
    } else if (idx < SW + BPTOT) {
        int b = idx - SW;
        const float* src; int FOUT; int o;
        if      (b < BP2)  { src=b1; FOUT=50;  o=b;        }
        else if (b < BP3)  { src=b2; FOUT=200; o=b-BP2;    }
        else if (b < BP4)  { src=b3; FOUT=500; o=b-BP3;    }
        else if (b < BP5)  { src=b4; FOUT=200; o=b-BP4;    }
        else               { src=b5; FOUT=100; o=b-BP5;    }
        biasP[b] = (o < FOUT) ? src[o] : 0.f;
    }
}

// ---------------- one MFMA layer (2-stage pipelined K-loop) ----------------
// Planes (LDS, stride STR halves): vhi, vlo (split v-state), dhi, ddh (fp16 d/dd).
// B-frag: lane l -> col = l&15 (sample), k0 = (l>>4)*8 + kt*32.
// A-frag: u32 element offset against uniform bases whi/wlo (saddr+voffset).
// C/D: col(lane&15)=sample, row((lane>>4)*4+reg)=output neuron.
// Per (kt,mt): 5 MFMAs: v: Ahi*Bvh + Ahi*Bvl + Alo*Bvh ; d: Ahi*Bdh ; dd: Ahi*Bdd.
template<int KP, int MTILES, int NMT, int NWACT, int FOUT, bool TANH, bool ADBUF>
__device__ __forceinline__ void layer_mfma(
    const _Float16* __restrict__ whi, const _Float16* __restrict__ wlo,
    int wcoff,                               // uniform element offset of this layer's plane
    const float* __restrict__ biasP,
    _Float16* vhi, _Float16* vlo, _Float16* dhi, _Float16* ddh,
    int lane, int wv)
{
    constexpr int KT = KP / 32;
    const int colS = lane & 15;
    const int kg   = lane >> 4;
    const bool act = (wv < NWACT);

    f4 accv[NMT], accd[NMT], accdd[NMT];

    if (act) {
#pragma unroll
        for (int i = 0; i < NMT; ++i) {
            accv[i]  = (f4){0.f, 0.f, 0.f, 0.f};
            accd[i]  = (f4){0.f, 0.f, 0.f, 0.f};
            accdd[i] = (f4){0.f, 0.f, 0.f, 0.f};
        }

        const int boff = colS * STR + kg * 8;

        unsigned woff[NMT];                 // u32 element offsets
#pragma unroll
        for (int i = 0; i < NMT; ++i) {
            int mt  = wv + NWACT * i;
            int mtc = mt < MTILES ? mt : MTILES - 1;
            woff[i] = (unsigned)(wcoff + (mtc * 16 + colS) * KP + kg * 8);
        }

        // 2-stage pipeline registers
        h8 Bp[2][4];                        // [parity][vh,vl,dh,dd]
        h8 Ap[2][NMT][2];                   // [parity][mt][hi,lo]  (only if ADBUF)

        // prime kt = 0
        Bp[0][0] = *(const h8*)(vhi + boff);
        Bp[0][1] = *(const h8*)(vlo + boff);
        Bp[0][2] = *(const h8*)(dhi + boff);
        Bp[0][3] = *(const h8*)(ddh + boff);
        if constexpr (ADBUF) {
#pragma unroll
            for (int i = 0; i < NMT; ++i) {
                Ap[0][i][0] = *(const h8*)(whi + woff[i]);
                Ap[0][i][1] = *(const h8*)(wlo + woff[i]);
            }
        }

#pragma unroll 2
        for (int kt = 0; kt < KT; ++kt) {
            const int cur = kt & 1, nxt = cur ^ 1;
            // prefetch kt+1 operands during kt's MFMA bundle
            if (kt + 1 < KT) {
                const int kb1 = (kt + 1) * 32;
                Bp[nxt][0] = *(const h8*)(vhi + boff + kb1);
                Bp[nxt][1] = *(const h8*)(vlo + boff + kb1);
                Bp[nxt][2] = *(const h8*)(dhi + boff + kb1);
                Bp[nxt][3] = *(const h8*)(ddh + boff + kb1);
                if constexpr (ADBUF) {
#pragma unroll
                    for (int i = 0; i < NMT; ++i) {
                        Ap[nxt][i][0] = *(const h8*)(whi + woff[i] + kb1);
                        Ap[nxt][i][1] = *(const h8*)(wlo + woff[i] + kb1);
                    }
                }
            }
            // non-dbuf A path: issue ALL m-tiles' loads before any MFMA consumes
            h8 At[NMT][2];
            if constexpr (!ADBUF) {
                const int kb = kt * 32;
#pragma unroll
                for (int i = 0; i < NMT; ++i) {
                    At[i][0] = *(const h8*)(whi + woff[i] + kb);
                    At[i][1] = *(const h8*)(wlo + woff[i] + kb);
                }
            }
#pragma unroll
            for (int i = 0; i < NMT; ++i) {
                if (wv + NWACT * i < MTILES) {
                    h8 Ahi = ADBUF ? Ap[cur][i][0] : At[i][0];
                    h8 Alo = ADBUF ? Ap[cur][i][1] : At[i][1];
                    accv[i]  = __builtin_amdgcn_mfma_f32_16x16x32_f16(Ahi, Bp[cur][0], accv[i],  0, 0, 0);
                    accv[i]  = __builtin_amdgcn_mfma_f32_16x16x32_f16(Ahi, Bp[cur][1], accv[i],  0, 0, 0);
                    accv[i]  = __builtin_amdgcn_mfma_f32_16x16x32_f16(Alo, Bp[cur][0], accv[i],  0, 0, 0);
                    accd[i]  = __builtin_amdgcn_mfma_f32_16x16x32_f16(Ahi, Bp[cur][2], accd[i],  0, 0, 0);
                    accdd[i] = __builtin_amdgcn_mfma_f32_16x16x32_f16(Ahi, Bp[cur][3], accdd[i], 0, 0, 0);
                }
            }
        }
    }
    __syncthreads();   // all reads of planes complete before in-place overwrite

    if (act) {
#pragma unroll
        for (int i = 0; i < NMT; ++i) {
            int mt = wv + NWACT * i;
            if (mt < MTILES) {
                int o0 = mt * 16 + kg * 4;
                f4 bi = *(const f4*)(biasP + o0);
                h4 pvh, pvl, pdh, pdd;
#pragma unroll
                for (int r = 0; r < 4; ++r) {
                    float zv  = accv[i][r] + bi[r];
                    float zd  = accd[i][r];
                    float zdd = accdd[i][r];
                    float ov, od, odd;
                    if constexpr (TANH) {
                        float t  = fast_tanh(zv);
                        float s2 = 1.0f - t * t;
                        ov  = t;
                        od  = s2 * zd;
                        odd = s2 * zdd - 2.0f * t * s2 * zd * zd;
                    } else {
                        ov = zv; od = zd; odd = zdd;
                    }
                    if (o0 + r >= FOUT) { ov = 0.f; od = 0.f; odd = 0.f; }
                    Split sv = split16(ov);
                    pvh[r] = sv.hi; pvl[r] = sv.lo;
                    pdh[r] = (_Float16)od;
                    pdd[r] = (_Float16)odd;
                }
                int off = colS * STR + o0;
                *(h4*)(vhi + off) = pvh;
                *(h4*)(vlo + off) = pvl;
                *(h4*)(dhi + off) = pdh;
                *(h4*)(ddh + off) = pdd;
            }
        }
    }
    __syncthreads();
}

// ---------------- main fused kernel ----------------
__global__ __launch_bounds__(THREADS, 4) void pinn_mfma(
    const float* __restrict__ W0, const float* __restrict__ b0,
    const float* __restrict__ x,  const float* __restrict__ A,
    const float* __restrict__ bvec,
    const _Float16* __restrict__ whi, const float* __restrict__ biasP,
    float* __restrict__ out)
{
    __shared__ __align__(16) _Float16 smem[4 * BS * STR];   // 66,560 B
    __shared__ float xs[BS];

    _Float16* vhi = smem + 0 * BS * STR;
    _Float16* vlo = smem + 1 * BS * STR;
    _Float16* dhi = smem + 2 * BS * STR;
    _Float16* ddh = smem + 3 * BS * STR;
    // Fm/Um overlay the plane space after the last MFMA layer's barrier
    float* Fm = (float*)smem;              // 16 x 104 floats
    float* Um = Fm + BS * 104;

    const int tid  = threadIdx.x;
    const int bid  = blockIdx.x;
    const int lane = tid & 63;
    const int wv   = tid >> 6;
    const _Float16* wlo = whi + SW;

    if (tid < BS) xs[tid] = x[bid * BS + tid];
    __syncthreads();

    // ---- layer 0: 1 -> 20, write padded-K (32) input planes ----
    {
        int s = tid >> 5;       // 0..15
        int k = tid & 31;       // 0..31
        float v0 = 0.f, v1 = 0.f, v2 = 0.f;
        if (k < 20) {
            float w  = W0[k];
            float z  = w * xs[s] + b0[k];
            float t  = fast_tanh(z);
            float s2 = 1.0f - t * t;
            v0 = t; v1 = s2 * w; v2 = -2.0f * t * s2 * w * w;
        }
        Split s0 = split16(v0);
        int off = s * STR + k;
        vhi[off] = s0.hi;           vlo[off] = s0.lo;
        dhi[off] = (_Float16)v1;    ddh[off] = (_Float16)v2;
    }
    __syncthreads();

    //          KP   MT NMT NWA FOUT       ADBUF
    layer_mfma< 32,  4, 1,  4,  50, true,  true >(whi, wlo, C1, biasP + BP1, vhi, vlo, dhi, ddh, lane, wv);
    layer_mfma< 64, 14, 2,  7, 200, true,  true >(whi, wlo, C2, biasP + BP2, vhi, vlo, dhi, ddh, lane, wv);
    layer_mfma<224, 32, 4,  8, 500, true,  false>(whi, wlo, C3, biasP + BP3, vhi, vlo, dhi, ddh, lane, wv);
    layer_mfma<512, 14, 2,  7, 200, true,  true >(whi, wlo, C4, biasP + BP4, vhi, vlo, dhi, ddh, lane, wv);

    // ---- layer 5: 200 -> 100 linear (pipelined), epilogue -> U, Uxx, F ----
    {
        constexpr int KP = 224, KT = 7, MTILES = 7, NWACT = 7;
        const int colS = lane & 15;
        const int kg   = lane >> 4;
        const bool act = (wv < NWACT);
        f4 av = (f4){0.f,0.f,0.f,0.f}, ad = av, add = av;
        if (act) {
            const int boff = colS * STR + kg * 8;
            const unsigned w5off = (unsigned)(C5 + (wv*16 + colS)*KP + kg*8);
            h8 Bp[2][4], Ap[2][2];
            Bp[0][0] = *(const h8*)(vhi + boff);
            Bp[0][1] = *(const h8*)(vlo + boff);
            Bp[0][2] = *(const h8*)(dhi + boff);
            Bp[0][3] = *(const h8*)(ddh + boff);
            Ap[0][0] = *(const h8*)(whi + w5off);
            Ap[0][1] = *(const h8*)(wlo + w5off);
#pragma unroll 2
            for (int kt = 0; kt < KT; ++kt) {
                const int cur = kt & 1, nxt = cur ^ 1;
                if (kt + 1 < KT) {
                    const int kb1 = (kt + 1) * 32;
                    Bp[nxt][0] = *(const h8*)(vhi + boff + kb1);
                    Bp[nxt][1] = *(const h8*)(vlo + boff + kb1);
                    Bp[nxt][2] = *(const h8*)(dhi + boff + kb1);
                    Bp[nxt][3] = *(const h8*)(ddh + boff + kb1);
                    Ap[nxt][0] = *(const h8*)(whi + w5off + kb1);
                    Ap[nxt][1] = *(const h8*)(wlo + w5off + kb1);
                }
                av  = __builtin_amdgcn_mfma_f32_16x16x32_f16(Ap[cur][0], Bp[cur][0], av,  0, 0, 0);
                av  = __builtin_amdgcn_mfma_f32_16x16x32_f16(Ap[cur][0], Bp[cur][1], av,  0, 0, 0);
                av  = __builtin_amdgcn_mfma_f32_16x16x32_f16(Ap[cur][1], Bp[cur][0], av,  0, 0, 0);
                ad  = __builtin_amdgcn_mfma_f32_16x16x32_f16(Ap[cur][0], Bp[cur][2], ad,  0, 0, 0);
                add = __builtin_amdgcn_mfma_f32_16x16x32_f16(Ap[cur][0], Bp[cur][3], add, 0, 0, 0);
            }
        }
        __syncthreads();   // planes dead after this point; overlay Fm/Um
        if (act) {
            int o0 = wv * 16 + kg * 4;
            f4 bi = *(const f4*)(biasP + BP5 + o0);
            float xv = xs[colS];
            float xm = xv * xv - 1.0f;
#pragma unroll
            for (int r = 0; r < 4; ++r) {
                int q = o0 + r;
                if (q < Q) {
                    float gv  = av[r] + bi[r];
                    float gd  = ad[r];
                    float gdd = add[r];
                    float U   = -1.0f + xm * gv;
                    float Uxx = 2.0f * gv + 4.0f * xv * gd + xm * gdd;
                    float Fv  = 5.0f * U * U * U - 5.0f * U - 0.0005f * Uxx;
                    Fm[colS * 104 + q] = Fv;
                    Um[colS * 104 + q] = U;
                }
            }
        }
        __syncthreads();
    }

    // ---- tail: U0 = U + DT*F@A^T ; U1 = U0 - DT*(F@bvec^T) (fp32 vector) ----
    {
        int qc = tid & 31;          // candidate q (and q+32, q+64, q+96)
        int ss = tid >> 5;          // sample 0..15
        float accq[4] = {0.f, 0.f, 0.f, 0.f};
        float cb = 0.f;
        const float* Fr = Fm + ss * 104;
#pragma unroll 5
        for (int j = 0; j < Q; j += 4) {
            f4 f4v = *(const f4*)(Fr + j);
            f4 bv4 = *(const f4*)(bvec + j);
            cb += f4v[0]*bv4[0] + f4v[1]*bv4[1] + f4v[2]*bv4[2] + f4v[3]*bv4[3];
#pragma unroll
            for (int u = 0; u < 4; ++u) {
                int q   = qc + 32 * u;
                int qcl = q < Q ? q : Q - 1;
                f4 a4 = *(const f4*)(A + qcl * Q + j);
                accq[u] += f4v[0]*a4[0] + f4v[1]*a4[1] + f4v[2]*a4[2] + f4v[3]*a4[3];
            }
        }
        int sg = bid * BS + ss;
#pragma unroll
        for (int u = 0; u < 4; ++u) {
            int q = qc + 32 * u;
            if (q < Q) {
                float U0 = Um[ss * 104 + q] + DTC * accq[u];
                float U1 = U0 - DTC * cb;
                out[sg * Q + q] = U0;
                out[NSAMP * Q + sg * Q + q] = U1;
            }
        }
    }
}

extern "C" void kernel_launch(void* const* d_in, const int* in_sizes, int n_in,
                              void* d_out, int out_size, void* d_ws, size_t ws_size,
                              hipStream_t stream) {
    const float* W0 = (const float*)d_in[0];
    const float* b0 = (const float*)d_in[1];
    const float* W1 = (const float*)d_in[2];
    const float* b1 = (const float*)d_in[3];
    const float* W2 = (const float*)d_in[4];
    const float* b2 = (const float*)d_in[5];
    const float* W3 = (const float*)d_in[6];
    const float* b3 = (const float*)d_in[7];
    const float* W4 = (const float*)d_in[8];
    const float* b4 = (const float*)d_in[9];
    const float* W5 = (const float*)d_in[10];
    const float* b5 = (const float*)d_in[11];
    const float* x  = (const float*)d_in[12];
    const float* A  = (const float*)d_in[13];
    const float* bv = (const float*)d_in[14];
    float* out = (float*)d_out;

    _Float16* whi = (_Float16*)d_ws;
    float* biasP  = (float*)((char*)d_ws + WS_BIAS_BYTE_OFF);

    prepass<<<(SW + BPTOT + 255) / 256, 256, 0, stream>>>(
        W1, b1, W2, b2, W3, b3, W4, b4, W5, b5, whi, biasP);

    pinn_mfma<<<NSAMP / BS, THREADS, 0, stream>>>(
        W0, b0, x, A, bv, whi, biasP, out);
}

// Round 10
// 450.366 us; speedup vs baseline: 1.4468x; 1.4468x over previous
//
#include <hip/hip_runtime.h>
#include <hip/hip_bf16.h>

// PINN fused forward+jvp^2 via split-fp16 MFMA.
// R10: weights pre-packed FRAGMENT-READY in the prepass: layout
// [mt][kt][lane][8 halves] so every A-fragment load in the hot K-loops is one
// fully-coalesced 1KB global_load_dwordx4 (2 cachelines) instead of R9's
// 16-cacheline scatter (rows strided 448-1024B). Inner loop reverted to R8's
// inline-load form (R9 dbuf was neutral). Structure unchanged otherwise:
// 4 LDS planes (vhi,vlo,dhi,ddh), 512 thr, 2 blocks/CU,
// 5 MFMA per (kt,mt): v = 3-product split-fp16, d/dd = plain fp16.

#define NSAMP 65536
#define Q     100
#define DTC   0.8f
#define BS    16
#define THREADS 512
#define STR   520          // LDS plane stride (halves)

typedef _Float16 h8 __attribute__((ext_vector_type(8)));
typedef _Float16 h4 __attribute__((ext_vector_type(4)));
typedef float    f4 __attribute__((ext_vector_type(4)));

// ---- packed fragment-ready weight geometry (halves) ----
// per layer: MT * KT * 512 halves (frag = 64 lanes x 8 halves)
// L1: MT=4,  KT=1  ->   2048
// L2: MT=14, KT=2  ->  14336
// L3: MT=32, KT=7  -> 114688
// L4: MT=14, KT=16 -> 114688
// L5: MT=7,  KT=7  ->  25088
#define SW 270848
#define C1 0
#define C2 2048
#define C3 16384
#define C4 131072
#define C5 245760
#define BP1 0
#define BP2 64
#define BP3 288
#define BP4 800
#define BP5 1024
#define BPTOT 1136
#define WS_BIAS_BYTE_OFF (SW*2*2)

__device__ __forceinline__ float fast_tanh(float z) {
    float az = fabsf(z);
    float e  = __expf(-2.0f * az);
    float r  = __builtin_amdgcn_rcpf(1.0f + e);
    float t  = (1.0f - e) * r;
    return copysignf(t, z);
}

struct Split { _Float16 hi, lo; };
__device__ __forceinline__ Split split16(float v) {
    Split s;
    s.hi = (_Float16)v;
    s.lo = (_Float16)(v - (float)s.hi);
    return s;
}

// ---------------- pre-pass: split/pad/PACK weights + biases into d_ws ----------------
// Packed element idx -> (frag = idx>>9, lane = (idx&511)>>3, e = idx&7)
// frag -> mt = frag/KT, kt = frag%KT; lane -> colS=lane&15, kg=lane>>4
// logical (o = mt*16+colS, k = kt*32+kg*8+e); zero outside [FOUT)x[K).
__global__ __launch_bounds__(256) void prepass(
    const float* __restrict__ W1, const float* __restrict__ b1,
    const float* __restrict__ W2, const float* __restrict__ b2,
    const float* __restrict__ W3, const float* __restrict__ b3,
    const float* __restrict__ W4, const float* __restrict__ b4,
    const float* __restrict__ W5, const float* __restrict__ b5,
    _Float16* __restrict__ whi, float* __restrict__ biasP)
{
    int idx = blockIdx.x * 256 + threadIdx.x;
    _Float16* wlo = whi + SW;
    if (idx < SW) {
        int base, KT, K, FOUT; const float* W;
        if      (idx < C2) { base=C1; KT=1;  K=20;  FOUT=50;  W=W1; }
        else if (idx < C3) { base=C2; KT=2;  K=50;  FOUT=200; W=W2; }
        else if (idx < C4) { base=C3; KT=7;  K=200; FOUT=500; W=W3; }
        else if (idx < C5) { base=C4; KT=16; K=500; FOUT=200; W=W4; }
        else               { base=C5; KT=7;  K=200; FOUT=100; W=W5; }
        int r    = idx - base;
        int frag = r >> 9;
        int f    = r & 511;
        int lane = f >> 3;
        int e    = f & 7;
        int colS = lane & 15;
        int kg   = lane >> 4;
        int mt   = frag / KT;
        int kt   = frag - mt * KT;
        int o = mt * 16 + colS;
        int k = kt * 32 + kg * 8 + e;
        float v = (o < FOUT && k < K) ? W[o * K + k] : 0.f;
        Split sp = split16(v);
        whi[idx] = sp.hi; wlo[idx] = sp.lo;
    } else if (idx < SW + BPTOT) {
        int b = idx - SW;
        const float* src; int FOUT; int o;
        if      (b < BP2)  { src=b1; FOUT=50;  o=b;        }
        else if (b < BP3)  { src=b2; FOUT=200; o=b-BP2;    }
        else if (b < BP4)  { src=b3; FOUT=500; o=b-BP3;    }
        else if (b < BP5)  { src=b4; FOUT=200; o=b-BP4;    }
        else               { src=b5; FOUT=100; o=b-BP5;    }
        biasP[b] = (o < FOUT) ? src[o] : 0.f;
    }
}

// ---------------- one MFMA layer ----------------
// Planes (LDS, stride STR halves): vhi, vlo (split v-state), dhi, ddh (fp16 d/dd).
// B-frag: lane l -> col = l&15 (sample), k0 = (l>>4)*8 + kt*32.
// A-frag: PACKED: base + (mt*KT + kt)*512 + lane*8  -> coalesced 1KB load.
// C/D: col(lane&15)=sample, row((lane>>4)*4+reg)=output neuron.
// Per (kt,mt): 5 MFMAs: v: Ahi*Bvh + Ahi*Bvl + Alo*Bvh ; d: Ahi*Bdh ; dd: Ahi*Bdd.
template<int KP, int MTILES, int NMT, int NWACT, int FOUT, bool TANH>
__device__ __forceinline__ void layer_mfma(
    const _Float16* __restrict__ whi, const _Float16* __restrict__ wlo,
    int wcoff,                               // uniform element offset of this layer's packed plane
    const float* __restrict__ biasP,
    _Float16* vhi, _Float16* vlo, _Float16* dhi, _Float16* ddh,
    int lane, int wv)
{
    constexpr int KT = KP / 32;
    const int colS = lane & 15;
    const int kg   = lane >> 4;
    const bool act = (wv < NWACT);

    f4 accv[NMT], accd[NMT], accdd[NMT];

    if (act) {
#pragma unroll
        for (int i = 0; i < NMT; ++i) {
            accv[i]  = (f4){0.f, 0.f, 0.f, 0.f};
            accd[i]  = (f4){0.f, 0.f, 0.f, 0.f};
            accdd[i] = (f4){0.f, 0.f, 0.f, 0.f};
        }

        const int boff = colS * STR + kg * 8;

        unsigned woff[NMT];                 // packed-fragment u32 element offsets
#pragma unroll
        for (int i = 0; i < NMT; ++i) {
            int mt  = wv + NWACT * i;
            int mtc = mt < MTILES ? mt : MTILES - 1;
            woff[i] = (unsigned)(wcoff + (mtc * KT) * 512 + lane * 8);
        }

#pragma unroll 2
        for (int kt = 0; kt < KT; ++kt) {
            const int kb  = kt * 32;        // LDS k offset (halves)
            const int kwb = kt * 512;       // packed weight offset (halves)
            h8 Bvh = *(const h8*)(vhi + boff + kb);
            h8 Bvl = *(const h8*)(vlo + boff + kb);
            h8 Bdh = *(const h8*)(dhi + boff + kb);
            h8 Bdd = *(const h8*)(ddh + boff + kb);
#pragma unroll
            for (int i = 0; i < NMT; ++i) {
                if (wv + NWACT * i < MTILES) {
                    h8 Ahi = *(const h8*)(whi + woff[i] + kwb);
                    h8 Alo = *(const h8*)(wlo + woff[i] + kwb);
                    accv[i]  = __builtin_amdgcn_mfma_f32_16x16x32_f16(Ahi, Bvh, accv[i],  0, 0, 0);
                    accv[i]  = __builtin_amdgcn_mfma_f32_16x16x32_f16(Ahi, Bvl, accv[i],  0, 0, 0);
                    accv[i]  = __builtin_amdgcn_mfma_f32_16x16x32_f16(Alo, Bvh, accv[i],  0, 0, 0);
                    accd[i]  = __builtin_amdgcn_mfma_f32_16x16x32_f16(Ahi, Bdh, accd[i],  0, 0, 0);
                    accdd[i] = __builtin_amdgcn_mfma_f32_16x16x32_f16(Ahi, Bdd, accdd[i], 0, 0, 0);
                }
            }
        }
    }
    __syncthreads();   // all reads of planes complete before in-place overwrite

    if (act) {
#pragma unroll
        for (int i = 0; i < NMT; ++i) {
            int mt = wv + NWACT * i;
            if (mt < MTILES) {
                int o0 = mt * 16 + kg * 4;
                f4 bi = *(const f4*)(biasP + o0);
                h4 pvh, pvl, pdh, pdd;
#pragma unroll
                for (int r = 0; r < 4; ++r) {
                    float zv  = accv[i][r] + bi[r];
                    float zd  = accd[i][r];
                    float zdd = accdd[i][r];
                    float ov, od, odd;
                    if constexpr (TANH) {
                        float t  = fast_tanh(zv);
                        float s2 = 1.0f - t * t;
                        ov  = t;
                        od  = s2 * zd;
                        odd = s2 * zdd - 2.0f * t * s2 * zd * zd;
                    } else {
                        ov = zv; od = zd; odd = zdd;
                    }
                    if (o0 + r >= FOUT) { ov = 0.f; od = 0.f; odd = 0.f; }
                    Split sv = split16(ov);
                    pvh[r] = sv.hi; pvl[r] = sv.lo;
                    pdh[r] = (_Float16)od;
                    pdd[r] = (_Float16)odd;
                }
                int off = colS * STR + o0;
                *(h4*)(vhi + off) = pvh;
                *(h4*)(vlo + off) = pvl;
                *(h4*)(dhi + off) = pdh;
                *(h4*)(ddh + off) = pdd;
            }
        }
    }
    __syncthreads();
}

// ---------------- main fused kernel ----------------
__global__ __launch_bounds__(THREADS, 4) void pinn_mfma(
    const float* __restrict__ W0, const float* __restrict__ b0,
    const float* __restrict__ x,  const float* __restrict__ A,
    const float* __restrict__ bvec,
    const _Float16* __restrict__ whi, const float* __restrict__ biasP,
    float* __restrict__ out)
{
    __shared__ __align__(16) _Float16 smem[4 * BS * STR];   // 66,560 B
    __shared__ float xs[BS];

    _Float16* vhi = smem + 0 * BS * STR;
    _Float16* vlo = smem + 1 * BS * STR;
    _Float16* dhi = smem + 2 * BS * STR;
    _Float16* ddh = smem + 3 * BS * STR;
    // Fm/Um overlay the plane space after the last MFMA layer's barrier
    float* Fm = (float*)smem;              // 16 x 104 floats
    float* Um = Fm + BS * 104;

    const int tid  = threadIdx.x;
    const int bid  = blockIdx.x;
    const int lane = tid & 63;
    const int wv   = tid >> 6;
    const _Float16* wlo = whi + SW;

    if (tid < BS) xs[tid] = x[bid * BS + tid];
    __syncthreads();

    // ---- layer 0: 1 -> 20, write padded-K (32) input planes ----
    {
        int s = tid >> 5;       // 0..15
        int k = tid & 31;       // 0..31
        float v0 = 0.f, v1 = 0.f, v2 = 0.f;
        if (k < 20) {
            float w  = W0[k];
            float z  = w * xs[s] + b0[k];
            float t  = fast_tanh(z);
            float s2 = 1.0f - t * t;
            v0 = t; v1 = s2 * w; v2 = -2.0f * t * s2 * w * w;
        }
        Split s0 = split16(v0);
        int off = s * STR + k;
        vhi[off] = s0.hi;           vlo[off] = s0.lo;
        dhi[off] = (_Float16)v1;    ddh[off] = (_Float16)v2;
    }
    __syncthreads();

    //          KP   MT NMT NWA FOUT
    layer_mfma< 32,  4, 1,  4,  50, true>(whi, wlo, C1, biasP + BP1, vhi, vlo, dhi, ddh, lane, wv);
    layer_mfma< 64, 14, 2,  7, 200, true>(whi, wlo, C2, biasP + BP2, vhi, vlo, dhi, ddh, lane, wv);
    layer_mfma<224, 32, 4,  8, 500, true>(whi, wlo, C3, biasP + BP3, vhi, vlo, dhi, ddh, lane, wv);
    layer_mfma<512, 14, 2,  7, 200, true>(whi, wlo, C4, biasP + BP4, vhi, vlo, dhi, ddh, lane, wv);

    // ---- layer 5: 200 -> 100 linear, epilogue -> U, Uxx, F (overlay) ----
    {
        constexpr int KT = 7, MTILES = 7, NWACT = 7;
        const int colS = lane & 15;
        const int kg   = lane >> 4;
        const bool act = (wv < NWACT);
        f4 av = (f4){0.f,0.f,0.f,0.f}, ad = av, add = av;
        if (act) {
            const int boff = colS * STR + kg * 8;
            const unsigned w5off = (unsigned)(C5 + (wv * KT) * 512 + lane * 8);
#pragma unroll 2
            for (int kt = 0; kt < KT; ++kt) {
                const int kb  = kt * 32;
                const int kwb = kt * 512;
                h8 Bvh = *(const h8*)(vhi + boff + kb);
                h8 Bvl = *(const h8*)(vlo + boff + kb);
                h8 Bdh = *(const h8*)(dhi + boff + kb);
                h8 Bdd = *(const h8*)(ddh + boff + kb);
                h8 Ahi = *(const h8*)(whi + w5off + kwb);
                h8 Alo = *(const h8*)(wlo + w5off + kwb);
                av  = __builtin_amdgcn_mfma_f32_16x16x32_f16(Ahi, Bvh, av,  0, 0, 0);
                av  = __builtin_amdgcn_mfma_f32_16x16x32_f16(Ahi, Bvl, av,  0, 0, 0);
                av  = __builtin_amdgcn_mfma_f32_16x16x32_f16(Alo, Bvh, av,  0, 0, 0);
                ad  = __builtin_amdgcn_mfma_f32_16x16x32_f16(Ahi, Bdh, ad,  0, 0, 0);
                add = __builtin_amdgcn_mfma_f32_16x16x32_f16(Ahi, Bdd, add, 0, 0, 0);
            }
        }
        __syncthreads();   // planes dead after this point; overlay Fm/Um
        if (act) {
            int o0 = wv * 16 + kg * 4;
            f4 bi = *(const f4*)(biasP + BP5 + o0);
            float xv = xs[colS];
            float xm = xv * xv - 1.0f;
#pragma unroll
            for (int r = 0; r < 4; ++r) {
                int q = o0 + r;
                if (q < Q) {
                    float gv  = av[r] + bi[r];
                    float gd  = ad[r];
                    float gdd = add[r];
                    float U   = -1.0f + xm * gv;
                    float Uxx = 2.0f * gv + 4.0f * xv * gd + xm * gdd;
                    float Fv  = 5.0f * U * U * U - 5.0f * U - 0.0005f * Uxx;
                    Fm[colS * 104 + q] = Fv;
                    Um[colS * 104 + q] = U;
                }
            }
        }
        __syncthreads();
    }

    // ---- tail: U0 = U + DT*F@A^T ; U1 = U0 - DT*(F@bvec^T) (fp32 vector) ----
    {
        int qc = tid & 31;          // candidate q (and q+32, q+64, q+96)
        int ss = tid >> 5;          // sample 0..15
        float accq[4] = {0.f, 0.f, 0.f, 0.f};
        float cb = 0.f;
        const float* Fr = Fm + ss * 104;
#pragma unroll 5
        for (int j = 0; j < Q; j += 4) {
            f4 f4v = *(const f4*)(Fr + j);
            f4 bv4 = *(const f4*)(bvec + j);
            cb += f4v[0]*bv4[0] + f4v[1]*bv4[1] + f4v[2]*bv4[2] + f4v[3]*bv4[3];
#pragma unroll
            for (int u = 0; u < 4; ++u) {
                int q   = qc + 32 * u;
                int qcl = q < Q ? q : Q - 1;
                f4 a4 = *(const f4*)(A + qcl * Q + j);
                accq[u] += f4v[0]*a4[0] + f4v[1]*a4[1] + f4v[2]*a4[2] + f4v[3]*a4[3];
            }
        }
        int sg = bid * BS + ss;
#pragma unroll
        for (int u = 0; u < 4; ++u) {
            int q = qc + 32 * u;
            if (q < Q) {
                float U0 = Um[ss * 104 + q] + DTC * accq[u];
                float U1 = U0 - DTC * cb;
                out[sg * Q + q] = U0;
                out[NSAMP * Q + sg * Q + q] = U1;
            }
        }
    }
}

extern "C" void kernel_launch(void* const* d_in, const int* in_sizes, int n_in,
                              void* d_out, int out_size, void* d_ws, size_t ws_size,
                              hipStream_t stream) {
    const float* W0 = (const float*)d_in[0];
    const float* b0 = (const float*)d_in[1];
    const float* W1 = (const float*)d_in[2];
    const float* b1 = (const float*)d_in[3];
    const float* W2 = (const float*)d_in[4];
    const float* b2 = (const float*)d_in[5];
    const float* W3 = (const float*)d_in[6];
    const float* b3 = (const float*)d_in[7];
    const float* W4 = (const float*)d_in[8];
    const float* b4 = (const float*)d_in[9];
    const float* W5 = (const float*)d_in[10];
    const float* b5 = (const float*)d_in[11];
    const float* x  = (const float*)d_in[12];
    const float* A  = (const float*)d_in[13];
    const float* bv = (const float*)d_in[14];
    float* out = (float*)d_out;

    _Float16* whi = (_Float16*)d_ws;
    float* biasP  = (float*)((char*)d_ws + WS_BIAS_BYTE_OFF);

    prepass<<<(SW + BPTOT + 255) / 256, 256, 0, stream>>>(
        W1, b1, W2, b2, W3, b3, W4, b4, W5, b5, whi, biasP);

    pinn_mfma<<<NSAMP / BS, THREADS, 0, stream>>>(
        W0, b0, x, A, bv, whi, biasP, out);
}